// Round 7
// baseline (472.551 us; speedup 1.0000x reference)
//
#include <hip/hip_runtime.h>

// GCN 2-layer + edge dot decoder. Dims fixed: in=512, hid=128, out=64.
#define IN_C  512
#define HID_C 128
#define OUT_C 64

using short8 = __attribute__((ext_vector_type(8))) short;   // 8 bf16
using floatx4 = __attribute__((ext_vector_type(4))) float;  // mfma acc

__device__ inline unsigned short f2bf(float f) {  // RNE
    unsigned u = __builtin_bit_cast(unsigned, f);
    u += 0x7FFFu + ((u >> 16) & 1u);
    return (unsigned short)(u >> 16);
}
__device__ inline float bf2f(unsigned short h) {
    unsigned u = ((unsigned)h) << 16;
    return __builtin_bit_cast(float, u);
}

// split float4 -> packed bf16 hi (truncate) + bf16 lo (RNE of exact residual)
__device__ inline void split_f4(const float4 v, uint2& hp, uint2& lp) {
    unsigned u0 = __builtin_bit_cast(unsigned, v.x);
    unsigned u1 = __builtin_bit_cast(unsigned, v.y);
    unsigned u2 = __builtin_bit_cast(unsigned, v.z);
    unsigned u3 = __builtin_bit_cast(unsigned, v.w);
    hp.x = (u1 & 0xFFFF0000u) | (u0 >> 16);
    hp.y = (u3 & 0xFFFF0000u) | (u2 >> 16);
    float r0 = v.x - __builtin_bit_cast(float, u0 & 0xFFFF0000u);
    float r1 = v.y - __builtin_bit_cast(float, u1 & 0xFFFF0000u);
    float r2 = v.z - __builtin_bit_cast(float, u2 & 0xFFFF0000u);
    float r3 = v.w - __builtin_bit_cast(float, u3 & 0xFFFF0000u);
    lp.x = ((unsigned)f2bf(r0)) | (((unsigned)f2bf(r1)) << 16);
    lp.y = ((unsigned)f2bf(r2)) | (((unsigned)f2bf(r3)) << 16);
}

// ---------------- CSR build ----------------
__global__ void k_zero_int(int* __restrict__ p, int n) {
    int i = blockIdx.x * blockDim.x + threadIdx.x;
    if (i < n) p[i] = 0;
}

__global__ void k_count(const int* __restrict__ dst, int* __restrict__ cnt, int e) {
    int i = blockIdx.x * blockDim.x + threadIdx.x;
    if (i < e) atomicAdd(&cnt[dst[i]], 1);
}

__global__ void k_dinv(const int* __restrict__ cnt, float* __restrict__ dinv, int n) {
    int i = blockIdx.x * blockDim.x + threadIdx.x;
    if (i < n) dinv[i] = rsqrtf(1.0f + (float)cnt[i]);  // +1 self-loop
}

__global__ void k_blocksum(const int* __restrict__ cnt, int* __restrict__ bsum, int n) {
    __shared__ int sdata[256];
    int t = threadIdx.x;
    int i = blockIdx.x * 256 + t;
    sdata[t] = (i < n) ? cnt[i] : 0;
    __syncthreads();
    for (int s = 128; s > 0; s >>= 1) {
        if (t < s) sdata[t] += sdata[t + s];
        __syncthreads();
    }
    if (t == 0) bsum[blockIdx.x] = sdata[0];
}

__global__ void k_scanpartials(int* __restrict__ bsum, int nb) {
    __shared__ int sdata[256];
    int t = threadIdx.x;
    int orig = (t < nb) ? bsum[t] : 0;
    sdata[t] = orig;
    __syncthreads();
    for (int off = 1; off < 256; off <<= 1) {
        int v = (t >= off) ? sdata[t - off] : 0;
        __syncthreads();
        sdata[t] += v;
        __syncthreads();
    }
    if (t < nb) bsum[t] = sdata[t] - orig;  // exclusive
}

__global__ void k_scanfinal(const int* __restrict__ cnt, const int* __restrict__ bsum_ex,
                            int* __restrict__ row_ptr, int n, int e_total) {
    __shared__ int sdata[256];
    int t = threadIdx.x;
    int i = blockIdx.x * 256 + t;
    int orig = (i < n) ? cnt[i] : 0;
    sdata[t] = orig;
    __syncthreads();
    for (int off = 1; off < 256; off <<= 1) {
        int v = (t >= off) ? sdata[t - off] : 0;
        __syncthreads();
        sdata[t] += v;
        __syncthreads();
    }
    if (i < n) row_ptr[i] = sdata[t] - orig + bsum_ex[blockIdx.x];
    if (i == 0) row_ptr[n] = e_total;
}

__global__ void k_fill(const int* __restrict__ src, const int* __restrict__ dst,
                       const int* __restrict__ row_ptr, int* __restrict__ cur,
                       int* __restrict__ col, int e) {
    int i = blockIdx.x * blockDim.x + threadIdx.x;
    if (i < e) {
        int d = dst[i];
        int pos = atomicAdd(&cur[d], 1);
        col[row_ptr[d] + pos] = src[i];
    }
}

// ---------------- weight prep: W [K][N] fp32 -> Wt_hi/Wt_lo [N][K] bf16 (RNE) ----------------
__global__ void k_prep_w(const float* __restrict__ W, unsigned short* __restrict__ hi,
                         unsigned short* __restrict__ lo, int K, int N) {
    int i = blockIdx.x * blockDim.x + threadIdx.x;
    if (i >= K * N) return;
    int k = i / N, n = i % N;
    float v = W[i];
    unsigned short h = f2bf(v);
    float r = v - bf2f(h);
    hi[(long)n * K + k] = h;
    lo[(long)n * K + k] = f2bf(r);
}

// ---------------- tiled split-bf16 MFMA GEMM ----------------
// Block 256 thr = 4 waves in 2x2 (wr over 32-row halves, wc over BN/2-col halves).
// Tile: 64 rows x BN cols, BK=64.
// A fp32 [M][K]: global->reg->split(hi/lo bf16)->LDS, converted once per block.
// B bf16 hi/lo [BN][K] (pre-transposed): global->reg->LDS, shared by all waves.
// Pipeline per k-tile: sync -> regs->LDS -> sync -> prefetch(t+1) -> compute(t).
// LDS stride LP=68 shorts (34 dwords == 2 mod 32): b128 frag reads and uint4
// staging writes are both bank-balanced.
template <int K, int BN>
__global__ __launch_bounds__(256) void k_gemm_tile(
    const float* __restrict__ A, const unsigned short* __restrict__ Bth,
    const unsigned short* __restrict__ Btl, const float* __restrict__ dinv,
    float* __restrict__ Hs, int M) {
    constexpr int NIW = BN / 32;   // 16-col tiles per wave
    constexpr int MI = 2;          // 16-row tiles per wave
    constexpr int NT = K / 64;     // k-tiles
    constexpr int LP = 68;
    __shared__ __align__(16) unsigned short Ah[64 * LP];
    __shared__ __align__(16) unsigned short Al[64 * LP];
    __shared__ __align__(16) unsigned short Bh[BN * LP];
    __shared__ __align__(16) unsigned short Bl[BN * LP];

    const int tid = threadIdx.x;
    const int w = tid >> 6, lane = tid & 63;
    const int wr = w >> 1, wc = w & 1;
    const int m = lane & 15, quad = lane >> 4;
    const int m0 = blockIdx.x * 64;

    // A staging: row sr (0..63), k-quarter sq (16 floats = 4 float4)
    const int sr = tid & 63;
    const int sq = tid >> 6;
    int gm = m0 + sr;
    if (gm >= M) gm = M - 1;  // clamp: dup data, epilogue guarded
    const float* ga = A + (long)gm * K + sq * 16;

    // B staging: row sb, k-half hb (32 shorts = 4 uint4 each for hi/lo)
    const int sb = tid >> 1;
    const int hb = tid & 1;
    const bool bok = sb < BN;
    const unsigned short* gbh = Bth + (long)(bok ? sb : 0) * K + hb * 32;
    const unsigned short* gbl = Btl + (long)(bok ? sb : 0) * K + hb * 32;

    floatx4 acc[MI][NIW];
#pragma unroll
    for (int mi = 0; mi < MI; ++mi)
#pragma unroll
        for (int ni = 0; ni < NIW; ++ni) acc[mi][ni] = (floatx4){0.f, 0.f, 0.f, 0.f};

    float4 va[4];
    uint4 vbh[4], vbl[4];

    // preload tile 0
#pragma unroll
    for (int i = 0; i < 4; ++i) va[i] = *(const float4*)(ga + i * 4);
#pragma unroll
    for (int i = 0; i < 4; ++i) {
        vbh[i] = *(const uint4*)(gbh + i * 8);
        vbl[i] = *(const uint4*)(gbl + i * 8);
    }

    for (int t = 0; t < NT; ++t) {
        __syncthreads();  // previous tile's compute done -> LDS reusable
        // regs -> LDS
        {
            uint4 hq[2], lq[2];
#pragma unroll
            for (int j = 0; j < 2; ++j) {
                uint2 h0, l0, h1, l1;
                split_f4(va[2 * j + 0], h0, l0);
                split_f4(va[2 * j + 1], h1, l1);
                hq[j].x = h0.x; hq[j].y = h0.y; hq[j].z = h1.x; hq[j].w = h1.y;
                lq[j].x = l0.x; lq[j].y = l0.y; lq[j].z = l1.x; lq[j].w = l1.y;
            }
            const int base = sr * LP + sq * 16;
            *(uint4*)&Ah[base + 0] = hq[0];
            *(uint4*)&Ah[base + 8] = hq[1];
            *(uint4*)&Al[base + 0] = lq[0];
            *(uint4*)&Al[base + 8] = lq[1];
            if (bok) {
                const int bb = sb * LP + hb * 32;
#pragma unroll
                for (int i = 0; i < 4; ++i) *(uint4*)&Bh[bb + 8 * i] = vbh[i];
#pragma unroll
                for (int i = 0; i < 4; ++i) *(uint4*)&Bl[bb + 8 * i] = vbl[i];
            }
        }
        __syncthreads();  // staging visible

        // prefetch next tile into regs (loads fly during compute below)
        if (t + 1 < NT) {
            const int k0 = (t + 1) * 64;
#pragma unroll
            for (int i = 0; i < 4; ++i) va[i] = *(const float4*)(ga + k0 + i * 4);
#pragma unroll
            for (int i = 0; i < 4; ++i) {
                vbh[i] = *(const uint4*)(gbh + k0 + i * 8);
                vbl[i] = *(const uint4*)(gbl + k0 + i * 8);
            }
        }

        // compute tile t from LDS
#pragma unroll
        for (int s = 0; s < 2; ++s) {
            short8 ah[MI], al[MI];
#pragma unroll
            for (int mi = 0; mi < MI; ++mi) {
                const int off = (wr * 32 + mi * 16 + m) * LP + s * 32 + quad * 8;
                ah[mi] = *(const short8*)&Ah[off];
                al[mi] = *(const short8*)&Al[off];
            }
            short8 bh[NIW], bl[NIW];
#pragma unroll
            for (int ni = 0; ni < NIW; ++ni) {
                const int off = (wc * (BN / 2) + ni * 16 + m) * LP + s * 32 + quad * 8;
                bh[ni] = *(const short8*)&Bh[off];
                bl[ni] = *(const short8*)&Bl[off];
            }
#pragma unroll
            for (int ni = 0; ni < NIW; ++ni)
#pragma unroll
                for (int mi = 0; mi < MI; ++mi) {
                    acc[mi][ni] = __builtin_amdgcn_mfma_f32_16x16x32_bf16(ah[mi], bh[ni], acc[mi][ni], 0, 0, 0);
                    acc[mi][ni] = __builtin_amdgcn_mfma_f32_16x16x32_bf16(ah[mi], bl[ni], acc[mi][ni], 0, 0, 0);
                    acc[mi][ni] = __builtin_amdgcn_mfma_f32_16x16x32_bf16(al[mi], bh[ni], acc[mi][ni], 0, 0, 0);
                }
        }
    }

    // epilogue: C/D layout col=lane&15, row=quad*4+reg; scale by dinv[row]
#pragma unroll
    for (int mi = 0; mi < MI; ++mi) {
#pragma unroll
        for (int r = 0; r < 4; ++r) {
            const int row = m0 + wr * 32 + mi * 16 + quad * 4 + r;
            if (row < M) {
                const float dv = dinv[row];
#pragma unroll
                for (int ni = 0; ni < NIW; ++ni) {
                    const int n = wc * (BN / 2) + ni * 16 + m;
                    Hs[(long)row * BN + n] = acc[mi][ni][r] * dv;
                }
            }
        }
    }
}

// ---------------- CSR aggregation, wave per node, 4x unrolled gathers ----------------
__global__ __launch_bounds__(256) void k_agg1(
    const float* __restrict__ h, const int* __restrict__ row_ptr,
    const int* __restrict__ col, const float* __restrict__ dinv,
    const float* __restrict__ bias, float* __restrict__ z, int n) {
    int node = blockIdx.x * 4 + (threadIdx.x >> 6);
    node = __builtin_amdgcn_readfirstlane(node);
    if (node >= n) return;
    int lane = threadIdx.x & 63;
    const float2* hp = (const float2*)h;
    float2 acc = hp[(long)node * 64 + lane];  // self-loop
    int rs = row_ptr[node], re = row_ptr[node + 1];
    int j = rs;
    for (; j + 4 <= re; j += 4) {
        int s0 = col[j], s1 = col[j + 1], s2 = col[j + 2], s3 = col[j + 3];
        float2 v0 = hp[(long)s0 * 64 + lane];
        float2 v1 = hp[(long)s1 * 64 + lane];
        float2 v2 = hp[(long)s2 * 64 + lane];
        float2 v3 = hp[(long)s3 * 64 + lane];
        acc.x += v0.x + v1.x + v2.x + v3.x;
        acc.y += v0.y + v1.y + v2.y + v3.y;
    }
    for (; j < re; ++j) {
        int s = col[j];
        float2 v = hp[(long)s * 64 + lane];
        acc.x += v.x;
        acc.y += v.y;
    }
    float dv = dinv[node];
    float2 b = ((const float2*)bias)[lane];
    acc.x = fmaxf(fmaf(acc.x, dv, b.x), 0.f);
    acc.y = fmaxf(fmaf(acc.y, dv, b.y), 0.f);
    ((float2*)z)[(long)node * 64 + lane] = acc;
}

__global__ __launch_bounds__(256) void k_agg2(
    const float* __restrict__ h, const int* __restrict__ row_ptr,
    const int* __restrict__ col, const float* __restrict__ dinv,
    const float* __restrict__ bias, float* __restrict__ z, int n) {
    int node = blockIdx.x * 4 + (threadIdx.x >> 6);
    node = __builtin_amdgcn_readfirstlane(node);
    if (node >= n) return;
    int lane = threadIdx.x & 63;
    float acc = h[(long)node * 64 + lane];  // self-loop
    int rs = row_ptr[node], re = row_ptr[node + 1];
    int j = rs;
    for (; j + 4 <= re; j += 4) {
        int s0 = col[j], s1 = col[j + 1], s2 = col[j + 2], s3 = col[j + 3];
        acc += h[(long)s0 * 64 + lane] + h[(long)s1 * 64 + lane] +
               h[(long)s2 * 64 + lane] + h[(long)s3 * 64 + lane];
    }
    for (; j < re; ++j) acc += h[(long)col[j] * 64 + lane];
    z[(long)node * 64 + lane] = fmaf(acc, dinv[node], bias[lane]);
}

// ---------------- decoder ----------------
__global__ void k_dot(const float* __restrict__ z2, const int* __restrict__ es,
                      const int* __restrict__ ed, float* __restrict__ out, int L) {
    int gid = blockIdx.x * blockDim.x + threadIdx.x;
    int wid = gid >> 6;
    int lane = threadIdx.x & 63;
    if (wid >= L) return;
    int a = es[wid], b = ed[wid];
    float v = z2[(long)a * OUT_C + lane] * z2[(long)b * OUT_C + lane];
#pragma unroll
    for (int off = 32; off > 0; off >>= 1) v += __shfl_down(v, off);
    if (lane == 0) out[wid] = v;
}

extern "C" void kernel_launch(void* const* d_in, const int* in_sizes, int n_in,
                              void* d_out, int out_size, void* d_ws, size_t ws_size,
                              hipStream_t stream) {
    const float* x = (const float*)d_in[0];
    const int* ei = (const int*)d_in[1];
    const int* eli = (const int*)d_in[2];
    const float* W1 = (const float*)d_in[3];
    const float* b1 = (const float*)d_in[4];
    const float* W2 = (const float*)d_in[5];
    const float* b2 = (const float*)d_in[6];
    float* out = (float*)d_out;

    const int N = in_sizes[0] / IN_C;  // 50000
    const int E = in_sizes[1] / 2;     // 800000
    const int L = in_sizes[2] / 2;     // 100000
    const int* src = ei;
    const int* dst = ei + E;
    const int* es = eli;
    const int* ed = eli + L;

    const int Npad = (N + 63) & ~63;
    const int Epad = (E + 3) & ~3;

    // workspace layout (~56 MB)
    int* cnt = (int*)d_ws;             // Npad
    int* cur = cnt + Npad;             // Npad
    int* row_ptr = cur + Npad;         // Npad + 64
    int* bsum = row_ptr + Npad + 64;   // 256
    int* col = bsum + 256;             // Epad
    float* dinv = (float*)(col + Epad);    // Npad
    float* h1s = dinv + Npad;              // N*128
    float* z1 = h1s + (long)N * HID_C;     // N*128
    float* h2s = h1s;                      // alias: h1s dead after agg1
    float* z2 = h1s + (long)N * OUT_C;     // alias: disjoint from h2s
    unsigned short* wt1_hi = (unsigned short*)(z1 + (long)N * HID_C);  // 512*128
    unsigned short* wt1_lo = wt1_hi + IN_C * HID_C;
    unsigned short* wt2_hi = wt1_lo + IN_C * HID_C;                    // 128*64
    unsigned short* wt2_lo = wt2_hi + HID_C * OUT_C;

    const int TPB = 256;
    const int nb = (N + 255) / 256;

    // weight prep
    k_prep_w<<<(IN_C * HID_C + TPB - 1) / TPB, TPB, 0, stream>>>(W1, wt1_hi, wt1_lo, IN_C, HID_C);
    k_prep_w<<<(HID_C * OUT_C + TPB - 1) / TPB, TPB, 0, stream>>>(W2, wt2_hi, wt2_lo, HID_C, OUT_C);

    // CSR build + dinv
    k_zero_int<<<(2 * Npad + TPB - 1) / TPB, TPB, 0, stream>>>(cnt, 2 * Npad);
    k_count<<<(E + TPB - 1) / TPB, TPB, 0, stream>>>(dst, cnt, E);
    k_dinv<<<(N + TPB - 1) / TPB, TPB, 0, stream>>>(cnt, dinv, N);
    k_blocksum<<<nb, 256, 0, stream>>>(cnt, bsum, N);
    k_scanpartials<<<1, 256, 0, stream>>>(bsum, nb);
    k_scanfinal<<<nb, 256, 0, stream>>>(cnt, bsum, row_ptr, N, E);
    k_fill<<<(E + TPB - 1) / TPB, TPB, 0, stream>>>(src, dst, row_ptr, cur, col, E);

    // layer 1: 64-row tiles, BN=128
    k_gemm_tile<IN_C, HID_C>
        <<<(N + 63) / 64, 256, 0, stream>>>(x, wt1_hi, wt1_lo, dinv, h1s, N);
    k_agg1<<<(N + 3) / 4, 256, 0, stream>>>(h1s, row_ptr, col, dinv, b1, z1, N);

    // layer 2: 64-row tiles, BN=64
    k_gemm_tile<HID_C, OUT_C>
        <<<(N + 63) / 64, 256, 0, stream>>>(z1, wt2_hi, wt2_lo, dinv, h2s, N);
    k_agg2<<<(N + 3) / 4, 256, 0, stream>>>(h2s, row_ptr, col, dinv, b2, z2, N);

    // decoder
    k_dot<<<((long)L * 64 + TPB - 1) / TPB, TPB, 0, stream>>>(z2, es, ed, out, L);
}

// Round 8
// 470.072 us; speedup vs baseline: 1.0053x; 1.0053x over previous
//
#include <hip/hip_runtime.h>

// GCN 2-layer + edge dot decoder. Dims fixed: in=512, hid=128, out=64.
#define IN_C  512
#define HID_C 128
#define OUT_C 64

using short8 = __attribute__((ext_vector_type(8))) short;   // 8 bf16
using floatx4 = __attribute__((ext_vector_type(4))) float;  // mfma acc

__device__ inline unsigned short f2bf(float f) {  // RNE
    unsigned u = __builtin_bit_cast(unsigned, f);
    u += 0x7FFFu + ((u >> 16) & 1u);
    return (unsigned short)(u >> 16);
}
__device__ inline float bf2f(unsigned short h) {
    unsigned u = ((unsigned)h) << 16;
    return __builtin_bit_cast(float, u);
}

// split float4 -> packed bf16 hi (truncate) + bf16 lo (RNE of exact residual)
__device__ inline void split_f4(const float4 v, uint2& hp, uint2& lp) {
    unsigned u0 = __builtin_bit_cast(unsigned, v.x);
    unsigned u1 = __builtin_bit_cast(unsigned, v.y);
    unsigned u2 = __builtin_bit_cast(unsigned, v.z);
    unsigned u3 = __builtin_bit_cast(unsigned, v.w);
    hp.x = (u1 & 0xFFFF0000u) | (u0 >> 16);
    hp.y = (u3 & 0xFFFF0000u) | (u2 >> 16);
    float r0 = v.x - __builtin_bit_cast(float, u0 & 0xFFFF0000u);
    float r1 = v.y - __builtin_bit_cast(float, u1 & 0xFFFF0000u);
    float r2 = v.z - __builtin_bit_cast(float, u2 & 0xFFFF0000u);
    float r3 = v.w - __builtin_bit_cast(float, u3 & 0xFFFF0000u);
    lp.x = ((unsigned)f2bf(r0)) | (((unsigned)f2bf(r1)) << 16);
    lp.y = ((unsigned)f2bf(r2)) | (((unsigned)f2bf(r3)) << 16);
}

// ---------------- CSR build ----------------
__global__ void k_zero_int(int* __restrict__ p, int n) {
    int i = blockIdx.x * blockDim.x + threadIdx.x;
    if (i < n) p[i] = 0;
}

__global__ void k_count(const int* __restrict__ dst, int* __restrict__ cnt, int e) {
    int i = blockIdx.x * blockDim.x + threadIdx.x;
    if (i < e) atomicAdd(&cnt[dst[i]], 1);
}

__global__ void k_dinv(const int* __restrict__ cnt, float* __restrict__ dinv, int n) {
    int i = blockIdx.x * blockDim.x + threadIdx.x;
    if (i < n) dinv[i] = rsqrtf(1.0f + (float)cnt[i]);  // +1 self-loop
}

__global__ void k_blocksum(const int* __restrict__ cnt, int* __restrict__ bsum, int n) {
    __shared__ int sdata[256];
    int t = threadIdx.x;
    int i = blockIdx.x * 256 + t;
    sdata[t] = (i < n) ? cnt[i] : 0;
    __syncthreads();
    for (int s = 128; s > 0; s >>= 1) {
        if (t < s) sdata[t] += sdata[t + s];
        __syncthreads();
    }
    if (t == 0) bsum[blockIdx.x] = sdata[0];
}

__global__ void k_scanpartials(int* __restrict__ bsum, int nb) {
    __shared__ int sdata[256];
    int t = threadIdx.x;
    int orig = (t < nb) ? bsum[t] : 0;
    sdata[t] = orig;
    __syncthreads();
    for (int off = 1; off < 256; off <<= 1) {
        int v = (t >= off) ? sdata[t - off] : 0;
        __syncthreads();
        sdata[t] += v;
        __syncthreads();
    }
    if (t < nb) bsum[t] = sdata[t] - orig;  // exclusive
}

__global__ void k_scanfinal(const int* __restrict__ cnt, const int* __restrict__ bsum_ex,
                            int* __restrict__ row_ptr, int n, int e_total) {
    __shared__ int sdata[256];
    int t = threadIdx.x;
    int i = blockIdx.x * 256 + t;
    int orig = (i < n) ? cnt[i] : 0;
    sdata[t] = orig;
    __syncthreads();
    for (int off = 1; off < 256; off <<= 1) {
        int v = (t >= off) ? sdata[t - off] : 0;
        __syncthreads();
        sdata[t] += v;
        __syncthreads();
    }
    if (i < n) row_ptr[i] = sdata[t] - orig + bsum_ex[blockIdx.x];
    if (i == 0) row_ptr[n] = e_total;
}

__global__ void k_fill(const int* __restrict__ src, const int* __restrict__ dst,
                       const int* __restrict__ row_ptr, int* __restrict__ cur,
                       int* __restrict__ col, int e) {
    int i = blockIdx.x * blockDim.x + threadIdx.x;
    if (i < e) {
        int d = dst[i];
        int pos = atomicAdd(&cur[d], 1);
        col[row_ptr[d] + pos] = src[i];
    }
}

// ---------------- weight prep: W [K][N] fp32 -> Wt_hi/Wt_lo [N][K] bf16 (RNE) ----------------
__global__ void k_prep_w(const float* __restrict__ W, unsigned short* __restrict__ hi,
                         unsigned short* __restrict__ lo, int K, int N) {
    int i = blockIdx.x * blockDim.x + threadIdx.x;
    if (i >= K * N) return;
    int k = i / N, n = i % N;
    float v = W[i];
    unsigned short h = f2bf(v);
    float r = v - bf2f(h);
    hi[(long)n * K + k] = h;
    lo[(long)n * K + k] = f2bf(r);
}

// ---------------- tiled split-bf16 MFMA GEMM ----------------
// Identical structure to R7; WPE (min waves/EU) raised the VGPR budget to 170
// (512/3) so the prefetch registers no longer spill to scratch (R7: VGPR=80,
// 180 MB scratch write traffic, 130 us). LDS caps occupancy at 3 blocks/CU
// anyway, so WPE=3 costs nothing.
template <int K, int BN, int WPE>
__global__ __launch_bounds__(256, WPE) void k_gemm_tile(
    const float* __restrict__ A, const unsigned short* __restrict__ Bth,
    const unsigned short* __restrict__ Btl, const float* __restrict__ dinv,
    float* __restrict__ Hs, int M) {
    constexpr int NIW = BN / 32;   // 16-col tiles per wave
    constexpr int MI = 2;          // 16-row tiles per wave
    constexpr int NT = K / 64;     // k-tiles
    constexpr int LP = 68;
    __shared__ __align__(16) unsigned short Ah[64 * LP];
    __shared__ __align__(16) unsigned short Al[64 * LP];
    __shared__ __align__(16) unsigned short Bh[BN * LP];
    __shared__ __align__(16) unsigned short Bl[BN * LP];

    const int tid = threadIdx.x;
    const int w = tid >> 6, lane = tid & 63;
    const int wr = w >> 1, wc = w & 1;
    const int m = lane & 15, quad = lane >> 4;
    const int m0 = blockIdx.x * 64;

    // A staging: row sr (0..63), k-quarter sq (16 floats = 4 float4)
    const int sr = tid & 63;
    const int sq = tid >> 6;
    int gm = m0 + sr;
    if (gm >= M) gm = M - 1;  // clamp: dup data, epilogue guarded
    const float* ga = A + (long)gm * K + sq * 16;

    // B staging: row sb, k-half hb (32 shorts = 4 uint4 each for hi/lo)
    const int sb = tid >> 1;
    const int hb = tid & 1;
    const bool bok = sb < BN;
    const unsigned short* gbh = Bth + (long)(bok ? sb : 0) * K + hb * 32;
    const unsigned short* gbl = Btl + (long)(bok ? sb : 0) * K + hb * 32;

    floatx4 acc[MI][NIW];
#pragma unroll
    for (int mi = 0; mi < MI; ++mi)
#pragma unroll
        for (int ni = 0; ni < NIW; ++ni) acc[mi][ni] = (floatx4){0.f, 0.f, 0.f, 0.f};

    float4 va[4];
    uint4 vbh[4], vbl[4];

    // preload tile 0
#pragma unroll
    for (int i = 0; i < 4; ++i) va[i] = *(const float4*)(ga + i * 4);
#pragma unroll
    for (int i = 0; i < 4; ++i) {
        vbh[i] = *(const uint4*)(gbh + i * 8);
        vbl[i] = *(const uint4*)(gbl + i * 8);
    }

    for (int t = 0; t < NT; ++t) {
        __syncthreads();  // previous tile's compute done -> LDS reusable
        // regs -> LDS
        {
            uint4 hq[2], lq[2];
#pragma unroll
            for (int j = 0; j < 2; ++j) {
                uint2 h0, l0, h1, l1;
                split_f4(va[2 * j + 0], h0, l0);
                split_f4(va[2 * j + 1], h1, l1);
                hq[j].x = h0.x; hq[j].y = h0.y; hq[j].z = h1.x; hq[j].w = h1.y;
                lq[j].x = l0.x; lq[j].y = l0.y; lq[j].z = l1.x; lq[j].w = l1.y;
            }
            const int base = sr * LP + sq * 16;
            *(uint4*)&Ah[base + 0] = hq[0];
            *(uint4*)&Ah[base + 8] = hq[1];
            *(uint4*)&Al[base + 0] = lq[0];
            *(uint4*)&Al[base + 8] = lq[1];
            if (bok) {
                const int bb = sb * LP + hb * 32;
#pragma unroll
                for (int i = 0; i < 4; ++i) *(uint4*)&Bh[bb + 8 * i] = vbh[i];
#pragma unroll
                for (int i = 0; i < 4; ++i) *(uint4*)&Bl[bb + 8 * i] = vbl[i];
            }
        }
        __syncthreads();  // staging visible

        // prefetch next tile into regs (loads fly during compute below)
        if (t + 1 < NT) {
            const int k0 = (t + 1) * 64;
#pragma unroll
            for (int i = 0; i < 4; ++i) va[i] = *(const float4*)(ga + k0 + i * 4);
#pragma unroll
            for (int i = 0; i < 4; ++i) {
                vbh[i] = *(const uint4*)(gbh + k0 + i * 8);
                vbl[i] = *(const uint4*)(gbl + k0 + i * 8);
            }
        }

        // compute tile t from LDS
#pragma unroll
        for (int s = 0; s < 2; ++s) {
            short8 ah[MI], al[MI];
#pragma unroll
            for (int mi = 0; mi < MI; ++mi) {
                const int off = (wr * 32 + mi * 16 + m) * LP + s * 32 + quad * 8;
                ah[mi] = *(const short8*)&Ah[off];
                al[mi] = *(const short8*)&Al[off];
            }
            short8 bh[NIW], bl[NIW];
#pragma unroll
            for (int ni = 0; ni < NIW; ++ni) {
                const int off = (wc * (BN / 2) + ni * 16 + m) * LP + s * 32 + quad * 8;
                bh[ni] = *(const short8*)&Bh[off];
                bl[ni] = *(const short8*)&Bl[off];
            }
#pragma unroll
            for (int ni = 0; ni < NIW; ++ni)
#pragma unroll
                for (int mi = 0; mi < MI; ++mi) {
                    acc[mi][ni] = __builtin_amdgcn_mfma_f32_16x16x32_bf16(ah[mi], bh[ni], acc[mi][ni], 0, 0, 0);
                    acc[mi][ni] = __builtin_amdgcn_mfma_f32_16x16x32_bf16(ah[mi], bl[ni], acc[mi][ni], 0, 0, 0);
                    acc[mi][ni] = __builtin_amdgcn_mfma_f32_16x16x32_bf16(al[mi], bh[ni], acc[mi][ni], 0, 0, 0);
                }
        }
    }

    // epilogue: C/D layout col=lane&15, row=quad*4+reg; scale by dinv[row]
#pragma unroll
    for (int mi = 0; mi < MI; ++mi) {
#pragma unroll
        for (int r = 0; r < 4; ++r) {
            const int row = m0 + wr * 32 + mi * 16 + quad * 4 + r;
            if (row < M) {
                const float dv = dinv[row];
#pragma unroll
                for (int ni = 0; ni < NIW; ++ni) {
                    const int n = wc * (BN / 2) + ni * 16 + m;
                    Hs[(long)row * BN + n] = acc[mi][ni][r] * dv;
                }
            }
        }
    }
}

// ---------------- CSR aggregation, wave per node, 4x unrolled gathers ----------------
__global__ __launch_bounds__(256) void k_agg1(
    const float* __restrict__ h, const int* __restrict__ row_ptr,
    const int* __restrict__ col, const float* __restrict__ dinv,
    const float* __restrict__ bias, float* __restrict__ z, int n) {
    int node = blockIdx.x * 4 + (threadIdx.x >> 6);
    node = __builtin_amdgcn_readfirstlane(node);
    if (node >= n) return;
    int lane = threadIdx.x & 63;
    const float2* hp = (const float2*)h;
    float2 acc = hp[(long)node * 64 + lane];  // self-loop
    int rs = row_ptr[node], re = row_ptr[node + 1];
    int j = rs;
    for (; j + 4 <= re; j += 4) {
        int s0 = col[j], s1 = col[j + 1], s2 = col[j + 2], s3 = col[j + 3];
        float2 v0 = hp[(long)s0 * 64 + lane];
        float2 v1 = hp[(long)s1 * 64 + lane];
        float2 v2 = hp[(long)s2 * 64 + lane];
        float2 v3 = hp[(long)s3 * 64 + lane];
        acc.x += v0.x + v1.x + v2.x + v3.x;
        acc.y += v0.y + v1.y + v2.y + v3.y;
    }
    for (; j < re; ++j) {
        int s = col[j];
        float2 v = hp[(long)s * 64 + lane];
        acc.x += v.x;
        acc.y += v.y;
    }
    float dv = dinv[node];
    float2 b = ((const float2*)bias)[lane];
    acc.x = fmaxf(fmaf(acc.x, dv, b.x), 0.f);
    acc.y = fmaxf(fmaf(acc.y, dv, b.y), 0.f);
    ((float2*)z)[(long)node * 64 + lane] = acc;
}

__global__ __launch_bounds__(256) void k_agg2(
    const float* __restrict__ h, const int* __restrict__ row_ptr,
    const int* __restrict__ col, const float* __restrict__ dinv,
    const float* __restrict__ bias, float* __restrict__ z, int n) {
    int node = blockIdx.x * 4 + (threadIdx.x >> 6);
    node = __builtin_amdgcn_readfirstlane(node);
    if (node >= n) return;
    int lane = threadIdx.x & 63;
    float acc = h[(long)node * 64 + lane];  // self-loop
    int rs = row_ptr[node], re = row_ptr[node + 1];
    int j = rs;
    for (; j + 4 <= re; j += 4) {
        int s0 = col[j], s1 = col[j + 1], s2 = col[j + 2], s3 = col[j + 3];
        acc += h[(long)s0 * 64 + lane] + h[(long)s1 * 64 + lane] +
               h[(long)s2 * 64 + lane] + h[(long)s3 * 64 + lane];
    }
    for (; j < re; ++j) acc += h[(long)col[j] * 64 + lane];
    z[(long)node * 64 + lane] = fmaf(acc, dinv[node], bias[lane]);
}

// ---------------- decoder ----------------
__global__ void k_dot(const float* __restrict__ z2, const int* __restrict__ es,
                      const int* __restrict__ ed, float* __restrict__ out, int L) {
    int gid = blockIdx.x * blockDim.x + threadIdx.x;
    int wid = gid >> 6;
    int lane = threadIdx.x & 63;
    if (wid >= L) return;
    int a = es[wid], b = ed[wid];
    float v = z2[(long)a * OUT_C + lane] * z2[(long)b * OUT_C + lane];
#pragma unroll
    for (int off = 32; off > 0; off >>= 1) v += __shfl_down(v, off);
    if (lane == 0) out[wid] = v;
}

extern "C" void kernel_launch(void* const* d_in, const int* in_sizes, int n_in,
                              void* d_out, int out_size, void* d_ws, size_t ws_size,
                              hipStream_t stream) {
    const float* x = (const float*)d_in[0];
    const int* ei = (const int*)d_in[1];
    const int* eli = (const int*)d_in[2];
    const float* W1 = (const float*)d_in[3];
    const float* b1 = (const float*)d_in[4];
    const float* W2 = (const float*)d_in[5];
    const float* b2 = (const float*)d_in[6];
    float* out = (float*)d_out;

    const int N = in_sizes[0] / IN_C;  // 50000
    const int E = in_sizes[1] / 2;     // 800000
    const int L = in_sizes[2] / 2;     // 100000
    const int* src = ei;
    const int* dst = ei + E;
    const int* es = eli;
    const int* ed = eli + L;

    const int Npad = (N + 63) & ~63;
    const int Epad = (E + 3) & ~3;

    // workspace layout (~56 MB)
    int* cnt = (int*)d_ws;             // Npad
    int* cur = cnt + Npad;             // Npad
    int* row_ptr = cur + Npad;         // Npad + 64
    int* bsum = row_ptr + Npad + 64;   // 256
    int* col = bsum + 256;             // Epad
    float* dinv = (float*)(col + Epad);    // Npad
    float* h1s = dinv + Npad;              // N*128
    float* z1 = h1s + (long)N * HID_C;     // N*128
    float* h2s = h1s;                      // alias: h1s dead after agg1
    float* z2 = h1s + (long)N * OUT_C;     // alias: disjoint from h2s
    unsigned short* wt1_hi = (unsigned short*)(z1 + (long)N * HID_C);  // 512*128
    unsigned short* wt1_lo = wt1_hi + IN_C * HID_C;
    unsigned short* wt2_hi = wt1_lo + IN_C * HID_C;                    // 128*64
    unsigned short* wt2_lo = wt2_hi + HID_C * OUT_C;

    const int TPB = 256;
    const int nb = (N + 255) / 256;

    // weight prep
    k_prep_w<<<(IN_C * HID_C + TPB - 1) / TPB, TPB, 0, stream>>>(W1, wt1_hi, wt1_lo, IN_C, HID_C);
    k_prep_w<<<(HID_C * OUT_C + TPB - 1) / TPB, TPB, 0, stream>>>(W2, wt2_hi, wt2_lo, HID_C, OUT_C);

    // CSR build + dinv
    k_zero_int<<<(2 * Npad + TPB - 1) / TPB, TPB, 0, stream>>>(cnt, 2 * Npad);
    k_count<<<(E + TPB - 1) / TPB, TPB, 0, stream>>>(dst, cnt, E);
    k_dinv<<<(N + TPB - 1) / TPB, TPB, 0, stream>>>(cnt, dinv, N);
    k_blocksum<<<nb, 256, 0, stream>>>(cnt, bsum, N);
    k_scanpartials<<<1, 256, 0, stream>>>(bsum, nb);
    k_scanfinal<<<nb, 256, 0, stream>>>(cnt, bsum, row_ptr, N, E);
    k_fill<<<(E + TPB - 1) / TPB, TPB, 0, stream>>>(src, dst, row_ptr, cur, col, E);

    // layer 1: 64-row tiles, BN=128
    k_gemm_tile<IN_C, HID_C, 3>
        <<<(N + 63) / 64, 256, 0, stream>>>(x, wt1_hi, wt1_lo, dinv, h1s, N);
    k_agg1<<<(N + 3) / 4, 256, 0, stream>>>(h1s, row_ptr, col, dinv, b1, z1, N);

    // layer 2: 64-row tiles, BN=64
    k_gemm_tile<HID_C, OUT_C, 3>
        <<<(N + 63) / 64, 256, 0, stream>>>(z1, wt2_hi, wt2_lo, dinv, h2s, N);
    k_agg2<<<(N + 3) / 4, 256, 0, stream>>>(h2s, row_ptr, col, dinv, b2, z2, N);

    // decoder
    k_dot<<<((long)L * 64 + TPB - 1) / TPB, TPB, 0, stream>>>(z2, es, ed, out, L);
}